// Round 2
// baseline (126.511 us; speedup 1.0000x reference)
//
#include <hip/hip_runtime.h>
#include <hip/hip_bf16.h>
#include <cstdint>
#include <cstddef>

#define NUM_CLASS 1000
#define NPAD      1024
#define LOW_DIM   128
#define B_UPD     1024
#define B_SIM     65536

typedef short bf16x8 __attribute__((ext_vector_type(8)));
typedef float f32x4  __attribute__((ext_vector_type(4)));

__device__ __forceinline__ unsigned short f2bf(float f) {
  union { float f; unsigned u; } a; a.f = f;
  unsigned u = a.u;
  return (unsigned short)((u + 0x7fffu + ((u >> 16) & 1u)) >> 16);  // RNE
}

// ---------- kernel 1: per-class sequential EMA + L2 normalize -> bf16 ----------
// Updates to different labels commute, so a per-class in-order scan reproduces
// the reference lax.scan exactly. Classes >= NUM_CLASS produce zero rows used
// as N-padding for the GEMM.
__global__ void proto_update_kernel(const float* __restrict__ pred_feat,
                                    const int*   __restrict__ labels,
                                    const float* __restrict__ protos_in,
                                    unsigned short* __restrict__ protos_bf) {
  int c = blockIdx.x;    // 0..1023
  int d = threadIdx.x;   // 0..127
  __shared__ int slab[B_UPD];
  for (int i = d; i < B_UPD; i += 128) slab[i] = labels[i];
  __syncthreads();

  float p = 0.0f;
  if (c < NUM_CLASS) {
    p = protos_in[c * LOW_DIM + d];
    const float M  = 0.99f;
    const float OM = 1.0f - 0.99f;
    for (int i = 0; i < B_UPD; ++i) {
      if (slab[i] == c) {
        p = M * p + OM * pred_feat[(size_t)i * LOW_DIM + d];
      }
    }
  }
  float sq = p * p;
  #pragma unroll
  for (int o = 1; o < 64; o <<= 1) sq += __shfl_xor(sq, o, 64);
  __shared__ float wsum[2];
  if ((d & 63) == 0) wsum[d >> 6] = sq;
  __syncthreads();
  float total = wsum[0] + wsum[1];
  float out = p / fmaxf(sqrtf(total), 1e-12f);
  protos_bf[c * LOW_DIM + d] = f2bf(out);
}

// ---------- kernel 2: C[65536,1000] = A[65536,128](f32->bf16) @ B[1024,128]^T ----------
// BM=BN=128, K=128 staged once. 4 waves x (64x64). f32 A converted to bf16
// in-register during staging (no separate cvt pass). XOR-swizzled bf16 LDS
// (both write and read sides). Epilogue: acc -> padded f32 LDS tile
// (stride 132 -> 2-way max write aliasing, conflict-free b128 readback) ->
// float4 nontemporal stores (16B/lane, 512B contiguous per 32 lanes).
#define BM  128
#define BN  128
#define TPB 256
#define CSTRIDE 132   // f32 epilogue LDS row stride (pad +4)

__global__ __launch_bounds__(TPB, 2)
void gemm_sim_kernel(const float* __restrict__ A,
                     const unsigned short* __restrict__ Bp,
                     float* __restrict__ C) {
  __shared__ unsigned char smem[BM * CSTRIDE * 4];  // 67.6 KB (union)
  unsigned char* Als = smem;                 // 32 KB bf16 A tile
  unsigned char* Bls = smem + 32 * 1024;     // 32 KB bf16 B tile
  float* Ctile = reinterpret_cast<float*>(smem);

  int bid  = blockIdx.x;                 // 4096 = 512 m-tiles x 8 n-tiles
  int xcd  = bid & 7, pos = bid >> 3;
  int orig = xcd * 512 + pos;            // bijective XCD swizzle (4096%8==0)
  int mblk = orig >> 3;                  // 8 consecutive orig ids share an A tile
  int nblk = orig & 7;
  int m0 = mblk * BM;
  int n0 = nblk * BN;
  int t  = threadIdx.x;

  // ---- stage A: 128 rows x 128 f32 -> bf16, swizzled ----
  #pragma unroll
  for (int it = 0; it < 8; ++it) {
    int idx = it * TPB + t;
    int row = idx >> 4, c8 = idx & 15;
    const float4* s = reinterpret_cast<const float4*>(A + (size_t)(m0 + row) * LOW_DIM + c8 * 8);
    float4 v0 = s[0], v1 = s[1];
    uint4 q;
    q.x = f2bf(v0.x) | ((unsigned)f2bf(v0.y) << 16);
    q.y = f2bf(v0.z) | ((unsigned)f2bf(v0.w) << 16);
    q.z = f2bf(v1.x) | ((unsigned)f2bf(v1.y) << 16);
    q.w = f2bf(v1.z) | ((unsigned)f2bf(v1.w) << 16);
    *reinterpret_cast<uint4*>(Als + row * 256 + ((c8 * 16) ^ ((row & 7) << 4))) = q;
  }
  // ---- stage B: 128 rows x 128 bf16 (protos, zero rows past 1000) ----
  #pragma unroll
  for (int it = 0; it < 8; ++it) {
    int idx = it * TPB + t;
    int row = idx >> 4, c8 = idx & 15;
    uint4 v = *reinterpret_cast<const uint4*>(Bp + (size_t)(n0 + row) * LOW_DIM + c8 * 8);
    *reinterpret_cast<uint4*>(Bls + row * 256 + ((c8 * 16) ^ ((row & 7) << 4))) = v;
  }
  __syncthreads();

  int lane = t & 63;
  int w    = t >> 6;
  int wr   = (w >> 1) * 64;
  int wc   = (w & 1) * 64;
  int lr   = lane & 15;
  int lkb  = (lane >> 4) * 16;

  f32x4 acc[4][4];
  #pragma unroll
  for (int m = 0; m < 4; ++m)
    #pragma unroll
    for (int n = 0; n < 4; ++n)
      acc[m][n] = (f32x4){0.f, 0.f, 0.f, 0.f};

  #pragma unroll
  for (int kk = 0; kk < 4; ++kk) {
    int kb = kk * 64 + lkb;
    bf16x8 af[4], bg[4];
    #pragma unroll
    for (int m = 0; m < 4; ++m) {
      int row = wr + m * 16 + lr;
      af[m] = *reinterpret_cast<const bf16x8*>(Als + row * 256 + (kb ^ ((row & 7) << 4)));
    }
    #pragma unroll
    for (int n = 0; n < 4; ++n) {
      int row = wc + n * 16 + lr;
      bg[n] = *reinterpret_cast<const bf16x8*>(Bls + row * 256 + (kb ^ ((row & 7) << 4)));
    }
    #pragma unroll
    for (int m = 0; m < 4; ++m)
      #pragma unroll
      for (int n = 0; n < 4; ++n)
        acc[m][n] = __builtin_amdgcn_mfma_f32_16x16x32_bf16(af[m], bg[n], acc[m][n], 0, 0, 0);
  }

  __syncthreads();   // all LDS reads done before reusing smem as Ctile

  // ---- acc -> padded f32 LDS tile ----
  // C/D layout: col = lane&15, row = (lane>>4)*4 + reg
  #pragma unroll
  for (int m = 0; m < 4; ++m) {
    int rbase = wr + m * 16 + (lane >> 4) * 4;
    #pragma unroll
    for (int n = 0; n < 4; ++n) {
      int col = wc + n * 16 + lr;
      #pragma unroll
      for (int r = 0; r < 4; ++r)
        Ctile[(rbase + r) * CSTRIDE + col] = acc[m][n][r];
    }
  }
  __syncthreads();

  // ---- readback + wide nontemporal stores ----
  #pragma unroll
  for (int it = 0; it < 16; ++it) {
    int idx = it * TPB + t;
    int row = idx >> 5;          // 0..127
    int c4  = idx & 31;          // float4 index within tile row
    int col = n0 + c4 * 4;
    f32x4 v = *reinterpret_cast<const f32x4*>(Ctile + row * CSTRIDE + c4 * 4);
    if (col < NUM_CLASS) {       // 1000 % 4 == 0: float4 never straddles edge
      __builtin_nontemporal_store(v,
        reinterpret_cast<f32x4*>(C + (size_t)(m0 + row) * NUM_CLASS + col));
    }
  }
}

extern "C" void kernel_launch(void* const* d_in, const int* in_sizes, int n_in,
                              void* d_out, int out_size, void* d_ws, size_t ws_size,
                              hipStream_t stream) {
  const float* pred_feat = (const float*)d_in[0];   // [1024,128]
  const int*   labels    = (const int*)d_in[1];     // [1024]
  const float* protos    = (const float*)d_in[2];   // [1000,128]
  const float* feat      = (const float*)d_in[3];   // [65536,128]
  float* out = (float*)d_out;                       // [65536,1000]

  unsigned short* protos_bf = (unsigned short*)d_ws;  // 1024x128 bf16 = 256 KB

  proto_update_kernel<<<NPAD, 128, 0, stream>>>(pred_feat, labels, protos, protos_bf);
  gemm_sim_kernel<<<(B_SIM / BM) * (NPAD / BN), TPB, 0, stream>>>(feat, protos_bf, out);
}

// Round 3
// 94.722 us; speedup vs baseline: 1.3356x; 1.3356x over previous
//
#include <hip/hip_runtime.h>
#include <hip/hip_bf16.h>
#include <cstdint>
#include <cstddef>

#define NUM_CLASS 1000
#define NPAD      1024
#define LOW_DIM   128
#define B_UPD     1024
#define B_SIM     65536

typedef short bf16x8 __attribute__((ext_vector_type(8)));
typedef float f32x4  __attribute__((ext_vector_type(4)));

__device__ __forceinline__ unsigned short f2bf(float f) {
  union { float f; unsigned u; } a; a.f = f;
  unsigned u = a.u;
  return (unsigned short)((u + 0x7fffu + ((u >> 16) & 1u)) >> 16);  // RNE
}

// ---------- kernel 1: per-class sequential EMA (ballot scan) + L2 norm -> bf16 ----------
// Updates to different labels commute, so per-class in-order processing
// reproduces the reference lax.scan exactly. Ballot turns the 1024-iteration
// serial scan into 16 ballots + ~1 match/class. Classes >= NUM_CLASS write
// zero rows (N-padding for the GEMM).
__global__ void proto_update_kernel(const float* __restrict__ pred_feat,
                                    const int*   __restrict__ labels,
                                    const float* __restrict__ protos_in,
                                    unsigned short* __restrict__ protos_bf) {
  int c = blockIdx.x;    // 0..1023
  int d = threadIdx.x;   // 0..127
  float p = 0.0f;
  if (c < NUM_CLASS) {
    p = protos_in[c * LOW_DIM + d];
    #pragma unroll 4
    for (int k = 0; k < B_UPD / 64; ++k) {
      int lab = labels[k * 64 + (d & 63)];
      unsigned long long m = __ballot(lab == c);   // wave-uniform
      while (m) {
        int b = __builtin_ctzll(m);
        m &= (m - 1);
        p = 0.99f * p + 0.01f * pred_feat[(size_t)(k * 64 + b) * LOW_DIM + d];
      }
    }
  }
  float sq = p * p;
  #pragma unroll
  for (int o = 1; o < 64; o <<= 1) sq += __shfl_xor(sq, o, 64);
  __shared__ float wsum[2];
  if ((d & 63) == 0) wsum[d >> 6] = sq;
  __syncthreads();
  float total = wsum[0] + wsum[1];
  protos_bf[c * LOW_DIM + d] = f2bf(p / fmaxf(sqrtf(total), 1e-12f));
}

// ---------- kernel 2: C[65536,1000] = A(f32->bf16) @ B[1024,128]^T ----------
// BM=64 x BN=1024 (FULL N): each block writes 64 complete rows = 250 KB
// CONTIGUOUS output -> fill-like write streaming. A read exactly once (no
// inter-block reuse). B = 256 KB total, L2-resident: fragments loaded
// directly from global per wave (no B staging, no main-loop barriers).
// 8 waves: wave w owns cols [w*128, w*128+128), all 64 rows.
#define BM   64
#define TPB2 512
#define CPAD 132                 // epilogue f32 LDS row stride
#define EPW  (16 * CPAD)         // floats per wave epilogue region (8448 B)

__global__ __launch_bounds__(TPB2)
void gemm_sim_kernel(const float* __restrict__ A,
                     const unsigned short* __restrict__ Bp,
                     float* __restrict__ C) {
  __shared__ unsigned char smem[8 * EPW * 4];   // 67584 B (union: A-tile 16 KB / epilogue)
  int t  = threadIdx.x;
  int m0 = blockIdx.x * BM;

  // ---- stage A: 64 rows x 128 f32 -> bf16, XOR-swizzled (rows 256 B) ----
  #pragma unroll
  for (int it = 0; it < 2; ++it) {
    int idx = it * TPB2 + t;
    int row = idx >> 4, c8 = idx & 15;
    const float4* s = reinterpret_cast<const float4*>(A + (size_t)(m0 + row) * LOW_DIM + c8 * 8);
    float4 v0 = s[0], v1 = s[1];
    uint4 q;
    q.x = f2bf(v0.x) | ((unsigned)f2bf(v0.y) << 16);
    q.y = f2bf(v0.z) | ((unsigned)f2bf(v0.w) << 16);
    q.z = f2bf(v1.x) | ((unsigned)f2bf(v1.y) << 16);
    q.w = f2bf(v1.z) | ((unsigned)f2bf(v1.w) << 16);
    *reinterpret_cast<uint4*>(smem + row * 256 + ((c8 * 16) ^ ((row & 7) << 4))) = q;
  }
  __syncthreads();

  int lane = t & 63;
  int w    = t >> 6;
  int lr   = lane & 15;
  int lkb  = (lane >> 4) * 16;                 // byte k-offset within 64-B group
  const unsigned char* Bw = reinterpret_cast<const unsigned char*>(Bp)
                          + (size_t)(w * 128) * 256;  // wave's 128 proto rows

  f32x4 acc[4][8];
  #pragma unroll
  for (int m = 0; m < 4; ++m)
    #pragma unroll
    for (int n = 0; n < 8; ++n)
      acc[m][n] = (f32x4){0.f, 0.f, 0.f, 0.f};

  #pragma unroll
  for (int kk = 0; kk < 4; ++kk) {             // K = 4 x 32
    int kb = kk * 64 + lkb;
    bf16x8 af[4];
    #pragma unroll
    for (int m = 0; m < 4; ++m) {
      int row = m * 16 + lr;
      af[m] = *reinterpret_cast<const bf16x8*>(smem + row * 256 + (kb ^ ((row & 7) << 4)));
    }
    #pragma unroll
    for (int n = 0; n < 8; ++n) {
      bf16x8 bf = *reinterpret_cast<const bf16x8*>(Bw + (size_t)(n * 16 + lr) * 256 + kb);
      #pragma unroll
      for (int m = 0; m < 4; ++m)
        acc[m][n] = __builtin_amdgcn_mfma_f32_16x16x32_bf16(af[m], bf, acc[m][n], 0, 0, 0);
    }
  }
  __syncthreads();   // A-tile dead for ALL waves before epilogue reuses smem

  // ---- per-wave-private LDS transpose epilogue (no block sync needed) ----
  float* myT = reinterpret_cast<float*>(smem) + w * EPW;
  #pragma unroll
  for (int m = 0; m < 4; ++m) {
    int rbase = (lane >> 4) * 4;
    #pragma unroll
    for (int n = 0; n < 8; ++n) {
      #pragma unroll
      for (int r = 0; r < 4; ++r)
        myT[(rbase + r) * CPAD + n * 16 + lr] = acc[m][n][r];
    }
    // wave-local RAW on LDS: compiler inserts lgkmcnt; DS ops in-order per wave
    #pragma unroll
    for (int it = 0; it < 8; ++it) {
      int idx = it * 64 + lane;
      int row = idx >> 5, c4 = idx & 31;
      f32x4 v = *reinterpret_cast<const f32x4*>(myT + row * CPAD + c4 * 4);
      int col = w * 128 + c4 * 4;
      if (col < NUM_CLASS) {   // only wave 7's tail lanes masked; 1000%4==0
        __builtin_nontemporal_store(v,
          reinterpret_cast<f32x4*>(C + (size_t)(m0 + m * 16 + row) * NUM_CLASS + col));
      }
    }
  }
}

extern "C" void kernel_launch(void* const* d_in, const int* in_sizes, int n_in,
                              void* d_out, int out_size, void* d_ws, size_t ws_size,
                              hipStream_t stream) {
  const float* pred_feat = (const float*)d_in[0];   // [1024,128]
  const int*   labels    = (const int*)d_in[1];     // [1024]
  const float* protos    = (const float*)d_in[2];   // [1000,128]
  const float* feat      = (const float*)d_in[3];   // [65536,128]
  float* out = (float*)d_out;                       // [65536,1000]

  unsigned short* protos_bf = (unsigned short*)d_ws;  // 1024x128 bf16 = 256 KB

  proto_update_kernel<<<NPAD, 128, 0, stream>>>(pred_feat, labels, protos, protos_bf);
  gemm_sim_kernel<<<B_SIM / BM, TPB2, 0, stream>>>(feat, protos_bf, out);
}

// Round 4
// 74.161 us; speedup vs baseline: 1.7059x; 1.2772x over previous
//
#include <hip/hip_runtime.h>
#include <hip/hip_bf16.h>
#include <cstdint>
#include <cstddef>

#define NUM_CLASS 1000
#define NPAD      1024
#define LOW_DIM   128
#define B_UPD     1024
#define B_SIM     65536

typedef short bf16x8 __attribute__((ext_vector_type(8)));
typedef float f32x4  __attribute__((ext_vector_type(4)));

__device__ __forceinline__ unsigned short f2bf(float f) {
  union { float f; unsigned u; } a; a.f = f;
  unsigned u = a.u;
  return (unsigned short)((u + 0x7fffu + ((u >> 16) & 1u)) >> 16);  // RNE
}

// ---------- kernel 1: per-class EMA (ballot scan) + L2 norm -> fragment-swizzled bf16 ----------
// Updates to different labels commute, so per-class in-order processing
// reproduces the reference lax.scan exactly.
// Output layout = MFMA B-fragment order so the GEMM's B loads are fully
// coalesced 1KB wave reads:
//   slot[((g*4 + kk)*64 + l) * 8 + e]  (ushort units)
//   holds logical B[row = g*16 + (l&15)][k = kk*32 + (l>>4)*8 + e]
// Thread (c,d): g=c>>4, r=c&15, kk=d>>5, j=(d>>3)&3, e=d&7 -> l=j*16+r.
__global__ void proto_update_kernel(const float* __restrict__ pred_feat,
                                    const int*   __restrict__ labels,
                                    const float* __restrict__ protos_in,
                                    unsigned short* __restrict__ protos_sw) {
  int c = blockIdx.x;    // 0..1023
  int d = threadIdx.x;   // 0..127
  float p = 0.0f;
  if (c < NUM_CLASS) {
    p = protos_in[c * LOW_DIM + d];
    #pragma unroll 4
    for (int k = 0; k < B_UPD / 64; ++k) {
      int lab = labels[k * 64 + (d & 63)];
      unsigned long long m = __ballot(lab == c);   // wave-uniform
      while (m) {
        int b = __builtin_ctzll(m);
        m &= (m - 1);
        p = 0.99f * p + 0.01f * pred_feat[(size_t)(k * 64 + b) * LOW_DIM + d];
      }
    }
  }
  float sq = p * p;
  #pragma unroll
  for (int o = 1; o < 64; o <<= 1) sq += __shfl_xor(sq, o, 64);
  __shared__ float wsum[2];
  if ((d & 63) == 0) wsum[d >> 6] = sq;
  __syncthreads();
  float total = wsum[0] + wsum[1];
  unsigned short v = f2bf(p / fmaxf(sqrtf(total), 1e-12f));  // c>=1000 -> 0
  int g = c >> 4, r = c & 15, kk = d >> 5, j = (d >> 3) & 3, e = d & 7;
  protos_sw[(size_t)((g * 4 + kk) * 64 + j * 16 + r) * 8 + e] = v;
}

// ---------- kernel 2: C[65536,1000] = A(f32->bf16) @ B^T, BM=32 x full-N ----------
// 8 waves; wave w owns 32 rows x cols [w*128, w*128+128). acc[2][8]=64 VGPR
// -> launch_bounds(512,4) keeps VGPR<=128 -> 2 blocks/CU resident (LDS 67.6KB):
// one block's stage/compute hides under the other's store drain.
// B loads: one coalesced 1KB read per (n,kk) from the fragment-swizzled panel.
#define BM   32
#define TPB2 512
#define CPAD 132                 // epilogue f32 LDS row stride (128+4)
#define EPW  (16 * CPAD)         // floats per wave epilogue region (8448 B)

__global__ __launch_bounds__(TPB2, 4)
void gemm_sim_kernel(const float* __restrict__ A,
                     const unsigned short* __restrict__ Bsw,
                     float* __restrict__ C) {
  __shared__ unsigned char smem[8 * EPW * 4];   // 67584 B (union: 8KB A-tile / epilogue)
  int t  = threadIdx.x;
  int m0 = blockIdx.x * BM;

  // ---- stage A: 32 rows x 128 f32 -> bf16, XOR-swizzled (rows 256 B) ----
  {
    int row = t >> 4, c8 = t & 15;   // 512 threads = 32 rows x 16 slots
    const float4* s = reinterpret_cast<const float4*>(A + (size_t)(m0 + row) * LOW_DIM + c8 * 8);
    float4 v0 = s[0], v1 = s[1];
    uint4 q;
    q.x = f2bf(v0.x) | ((unsigned)f2bf(v0.y) << 16);
    q.y = f2bf(v0.z) | ((unsigned)f2bf(v0.w) << 16);
    q.z = f2bf(v1.x) | ((unsigned)f2bf(v1.y) << 16);
    q.w = f2bf(v1.z) | ((unsigned)f2bf(v1.w) << 16);
    *reinterpret_cast<uint4*>(smem + row * 256 + ((c8 * 16) ^ ((row & 7) << 4))) = q;
  }
  __syncthreads();

  int lane = t & 63;
  int w    = t >> 6;
  int lr   = lane & 15;
  int lkb  = (lane >> 4) * 16;

  f32x4 acc[2][8];
  #pragma unroll
  for (int m = 0; m < 2; ++m)
    #pragma unroll
    for (int n = 0; n < 8; ++n)
      acc[m][n] = (f32x4){0.f, 0.f, 0.f, 0.f};

  #pragma unroll
  for (int kk = 0; kk < 4; ++kk) {             // K = 4 x 32
    int kb = kk * 64 + lkb;
    bf16x8 af[2];
    #pragma unroll
    for (int m = 0; m < 2; ++m) {
      int row = m * 16 + lr;
      af[m] = *reinterpret_cast<const bf16x8*>(smem + row * 256 + (kb ^ ((row & 7) << 4)));
    }
    #pragma unroll
    for (int n = 0; n < 8; ++n) {
      int g = w * 8 + n;                       // 16-row group of B
      bf16x8 bf = *reinterpret_cast<const bf16x8*>(
          Bsw + ((size_t)(g * 4 + kk) * 64 + lane) * 8);   // coalesced 1KB/wave
      #pragma unroll
      for (int m = 0; m < 2; ++m)
        acc[m][n] = __builtin_amdgcn_mfma_f32_16x16x32_bf16(af[m], bf, acc[m][n], 0, 0, 0);
    }
  }
  __syncthreads();   // A-tile dead for ALL waves before epilogue reuses smem

  // ---- per-wave-private LDS transpose epilogue (wave-local, in-order DS) ----
  float* myT = reinterpret_cast<float*>(smem) + w * EPW;
  #pragma unroll
  for (int m = 0; m < 2; ++m) {
    int rbase = (lane >> 4) * 4;
    #pragma unroll
    for (int n = 0; n < 8; ++n) {
      #pragma unroll
      for (int r = 0; r < 4; ++r)
        myT[(rbase + r) * CPAD + n * 16 + lr] = acc[m][n][r];
    }
    #pragma unroll
    for (int it = 0; it < 8; ++it) {
      int idx = it * 64 + lane;
      int row = idx >> 5, c4 = idx & 31;
      f32x4 v = *reinterpret_cast<const f32x4*>(myT + row * CPAD + c4 * 4);
      int col = w * 128 + c4 * 4;
      if (col < NUM_CLASS) {   // only wave 7 tail masked; 1000 % 4 == 0
        *reinterpret_cast<f32x4*>(C + (size_t)(m0 + m * 16 + row) * NUM_CLASS + col) = v;
      }
    }
  }
}

extern "C" void kernel_launch(void* const* d_in, const int* in_sizes, int n_in,
                              void* d_out, int out_size, void* d_ws, size_t ws_size,
                              hipStream_t stream) {
  const float* pred_feat = (const float*)d_in[0];   // [1024,128]
  const int*   labels    = (const int*)d_in[1];     // [1024]
  const float* protos    = (const float*)d_in[2];   // [1000,128]
  const float* feat      = (const float*)d_in[3];   // [65536,128]
  float* out = (float*)d_out;                       // [65536,1000]

  unsigned short* protos_sw = (unsigned short*)d_ws;  // 256 KB fragment-swizzled

  proto_update_kernel<<<NPAD, 128, 0, stream>>>(pred_feat, labels, protos, protos_sw);
  gemm_sim_kernel<<<B_SIM / BM, TPB2, 0, stream>>>(feat, protos_sw, out);
}